// Round 7
// baseline (18.188 us; speedup 1.0000x reference)
//
#include <hip/hip_runtime.h>
#include <hip/hip_bf16.h>
#include <math.h>

// Problem constants
#define B_TOT 256
#define P_P   1152
#define J_J   160        // L*O
#define K_K   9216       // N_N * P_P
#define L_L   10

// Split-K: slice sg owns k-subset {n*1152 + p : p in [64*sg, 64*sg+64), all n}
// Block-local k order: kk = dp*8 + n  (dp = p - 64*sg)
#define SG 18
#define JG 5

typedef __attribute__((ext_vector_type(8))) short short8;   // 8 x bf16
typedef __attribute__((ext_vector_type(4))) float f32x4;

__device__ __forceinline__ short f2bf(float f) {
    __hip_bfloat16 h = __float2bfloat16(f);   // native v_cvt (RNE) on gfx950
    return __builtin_bit_cast(short, h);
}

// ---------------------------------------------------------------------------
// Kernel 1: split-K MFMA GEMM reading x and W directly.
// grid = (8 bt, 18 sg, 5 jg), 256 threads = 4 waves, 128-VGPR budget.
// Block tile: 32 b x 32 j x 512 k; wave w owns kk in [w*128, w*128+128).
// Phase 1: stage x-tile -> As bf16 (ALL 64 loads in flight, then cvt+write).
// Phase 2: hoist ALL 16 W dwordx4, then 4 ks x 4 MFMA.
// Phase 3 (LDS reused): cross-wave split-K reduce, coalesced part stores.
// ---------------------------------------------------------------------------
__global__ __launch_bounds__(256, 4) void gemm_direct(const float* __restrict__ x,
                                                      const float* __restrict__ W,
                                                      float* __restrict__ part) {
    const int bt = blockIdx.x;      // 0..7
    const int sg = blockIdx.y;      // 0..17
    const int jg = blockIdx.z;      // 0..4
    const int tid  = threadIdx.x;
    const int w    = tid >> 6;      // wave 0..3
    const int lane = tid & 63;
    const int b0 = bt * 32;
    const int p0 = sg * 64;
    const int j0 = jg * 32;

    // Union: phase 1/2 use As (33.3 KB); phase 3 reuses it as redux (17.4 KB).
    __shared__ __align__(16) short As[32][520];   // rows padded: b128 reads spread evenly
    float (*redux)[64][17] = (float (*)[64][17])(&As[0][0]);  // +1 pad rows

    // ---- phase 1: stage x-tile; lane = dp, all 64 loads issued up front ----
    float xv[8][8];
    {
        const float* xb = x + (size_t)(b0 + w * 8) * K_K + p0 + lane;
        #pragma unroll
        for (int i = 0; i < 8; ++i)
            #pragma unroll
            for (int n = 0; n < 8; ++n)
                xv[i][n] = xb[(size_t)i * K_K + (size_t)n * P_P];
    }
    #pragma unroll
    for (int i = 0; i < 8; ++i) {
        short8 sh;
        #pragma unroll
        for (int n = 0; n < 8; ++n) sh[n] = f2bf(xv[i][n]);
        *reinterpret_cast<short8*>(&As[w * 8 + i][lane * 8]) = sh;  // kk = lane*8+n
    }
    __syncthreads();

    const int m  = lane & 15;
    const int kq = lane >> 4;       // 0..3

    // ---- phase 2: hoist all 16 B-loads, then MFMA chain ----
    // B: p = p0 + w*16 + ks*4 + kq, j = j0 + m (+16 for j-chain 1)
    const float* wbase = W + (size_t)(p0 + w * 16 + kq) * 1280 + (size_t)(j0 + m) * 8;
    f32x4 bv[4][4];
    #pragma unroll
    for (int ks = 0; ks < 4; ++ks) {
        const float* wp = wbase + (size_t)ks * 4 * 1280;
        bv[ks][0] = *reinterpret_cast<const f32x4*>(wp);
        bv[ks][1] = *reinterpret_cast<const f32x4*>(wp + 4);
        bv[ks][2] = *reinterpret_cast<const f32x4*>(wp + 128);
        bv[ks][3] = *reinterpret_cast<const f32x4*>(wp + 132);
    }

    f32x4 acc00 = {0.f,0.f,0.f,0.f}, acc01 = {0.f,0.f,0.f,0.f};
    f32x4 acc10 = {0.f,0.f,0.f,0.f}, acc11 = {0.f,0.f,0.f,0.f};

    #pragma unroll
    for (int ks = 0; ks < 4; ++ks) {
        const short8 af0 =
            *reinterpret_cast<const short8*>(&As[m][w * 128 + ks * 32 + kq * 8]);
        const short8 af1 =
            *reinterpret_cast<const short8*>(&As[m + 16][w * 128 + ks * 32 + kq * 8]);
        short8 bf0, bf1;
        #pragma unroll
        for (int e = 0; e < 4; ++e) {
            bf0[e]     = f2bf(bv[ks][0][e]);
            bf0[e + 4] = f2bf(bv[ks][1][e]);
            bf1[e]     = f2bf(bv[ks][2][e]);
            bf1[e + 4] = f2bf(bv[ks][3][e]);
        }
        acc00 = __builtin_amdgcn_mfma_f32_16x16x32_bf16(af0, bf0, acc00, 0, 0, 0);
        acc01 = __builtin_amdgcn_mfma_f32_16x16x32_bf16(af0, bf1, acc01, 0, 0, 0);
        acc10 = __builtin_amdgcn_mfma_f32_16x16x32_bf16(af1, bf0, acc10, 0, 0, 0);
        acc11 = __builtin_amdgcn_mfma_f32_16x16x32_bf16(af1, bf1, acc11, 0, 0, 0);
    }

    __syncthreads();   // all As reads done -> safe to overwrite via redux alias

    // ---- phase 3: cross-wave split-K reduce (deterministic order) ----
    #pragma unroll
    for (int r = 0; r < 4; ++r) {
        redux[w][lane][r]      = acc00[r];
        redux[w][lane][r + 4]  = acc01[r];
        redux[w][lane][r + 8]  = acc10[r];
        redux[w][lane][r + 12] = acc11[r];
    }
    __syncthreads();

    // 1024 outputs; consecutive lanes -> consecutive j (coalesced 128B stores)
    #pragma unroll
    for (int f = tid; f < 1024; f += 256) {
        const int bl = f >> 5;          // local b 0..31
        const int jl = f & 31;          // local j 0..31
        const int bi = bl >> 4;         // b half (af0/af1)
        const int kk = (bl >> 2) & 3;   // kq of the D-row
        const int r  = bl & 3;          // reg
        const int ji = jl >> 4;         // j half (bf0/bf1)
        const int mm = jl & 15;
        const int ln = kk * 16 + mm;
        const int c  = bi * 8 + ji * 4 + r;
        const float s = redux[0][ln][c] + redux[1][ln][c]
                      + redux[2][ln][c] + redux[3][ln][c];
        part[((size_t)(b0 + bl) * SG + sg) * J_J + j0 + jl] = s;
    }
}

// ---------------------------------------------------------------------------
// Kernel 2: reduce partials over slices + squash (norm over L axis) -> out
// part[b][si][j]: per-b strip is SG*160 floats contiguous.
// ---------------------------------------------------------------------------
__global__ __launch_bounds__(192) void reduce_squash(const float* __restrict__ part,
                                                     float* __restrict__ out) {
    const int b = blockIdx.x;
    const int j = threadIdx.x;
    __shared__ float sld[J_J];
    float s = 0.0f;
    if (j < J_J) {
        const float* pb = part + (size_t)b * SG * J_J + j;
        #pragma unroll 6
        for (int si = 0; si < SG; ++si)
            s += pb[(size_t)si * J_J];
        sld[j] = s;
    }
    __syncthreads();
    if (j < J_J) {
        const int o = j & 15;
        float msq = 0.0f;
        #pragma unroll
        for (int l = 0; l < L_L; ++l) {
            const float v = sld[l * 16 + o];
            msq = fmaf(v, v, msq);
        }
        const float mag = sqrtf(msq);
        out[(size_t)b * J_J + j] = s * (mag / (1.0f + msq));
    }
}

// ---------------------------------------------------------------------------
extern "C" void kernel_launch(void* const* d_in, const int* in_sizes, int n_in,
                              void* d_out, int out_size, void* d_ws, size_t ws_size,
                              hipStream_t stream) {
    const float* x = (const float*)d_in[0];   // (256, 8, 1152)
    const float* W = (const float*)d_in[1];   // (1, 1152, 10, 16, 8)
    float* out = (float*)d_out;               // (256, 10, 16)

    float* part = (float*)d_ws;               // [256][18][160] fp32 = 2.95 MB

    dim3 gg(B_TOT / 32, SG, JG);
    gemm_direct<<<gg, 256, 0, stream>>>(x, W, part);

    reduce_squash<<<B_TOT, 192, 0, stream>>>(part, out);
}

// Round 8
// 17.716 us; speedup vs baseline: 1.0266x; 1.0266x over previous
//
#include <hip/hip_runtime.h>
#include <hip/hip_bf16.h>
#include <math.h>

// Problem constants
#define B_TOT 256
#define P_P   1152
#define J_J   160        // L*O
#define K_K   9216       // N_N * P_P
#define L_L   10

// Split-K: slice sg owns k-subset {n*1152 + p : p in [64*sg, 64*sg+64), all n}
// Block-local k order: kk = dp*8 + n  (dp = p - 64*sg)
#define SG 18
#define JG 5

typedef __attribute__((ext_vector_type(8))) short short8;   // 8 x bf16
typedef __attribute__((ext_vector_type(4))) float f32x4;

__device__ __forceinline__ short f2bf(float f) {
    __hip_bfloat16 h = __float2bfloat16(f);   // native v_cvt (RNE) on gfx950
    return __builtin_bit_cast(short, h);
}

// ---------------------------------------------------------------------------
// Kernel 1: split-K MFMA GEMM reading x and W directly.
// grid = (8 bt, 18 sg, 5 jg), 256 threads = 4 waves.
// LDS union: As (33.3 KB) then redux (17.4 KB) -> 4 blocks/CU.
// launch_bounds(256,4): 128-VGPR cap, NO hand-hoisting (compiler pipelines;
// round 7 showed full xv+bv hoist spills past 128 and is neutral).
// Block tile: 32 b x 32 j x 512 k; wave w owns kk in [w*128, w*128+128).
// ---------------------------------------------------------------------------
__global__ __launch_bounds__(256, 4) void gemm_direct(const float* __restrict__ x,
                                                      const float* __restrict__ W,
                                                      float* __restrict__ part) {
    const int bt = blockIdx.x;      // 0..7
    const int sg = blockIdx.y;      // 0..17
    const int jg = blockIdx.z;      // 0..4
    const int tid  = threadIdx.x;
    const int w    = tid >> 6;      // wave 0..3
    const int lane = tid & 63;
    const int b0 = bt * 32;
    const int p0 = sg * 64;
    const int j0 = jg * 32;

    __shared__ __align__(16) short As[32][520];   // rows padded; 2-way alias only
    float (*redux)[64][17] = (float (*)[64][17])(&As[0][0]);  // union (17.4 KB)

    // ---- stage x-tile: lane = dp; coalesced dword loads, cvt, b128 write ----
    #pragma unroll
    for (int i = 0; i < 8; ++i) {
        const int bb = w * 8 + i;
        const float* xr = x + (size_t)(b0 + bb) * K_K + p0 + lane;
        short8 sh;
        #pragma unroll
        for (int n = 0; n < 8; ++n)
            sh[n] = f2bf(xr[(size_t)n * P_P]);
        *reinterpret_cast<short8*>(&As[bb][lane * 8]) = sh;  // kk = lane*8 + n
    }
    __syncthreads();

    const int m  = lane & 15;
    const int kq = lane >> 4;       // 0..3

    f32x4 acc00 = {0.f,0.f,0.f,0.f}, acc01 = {0.f,0.f,0.f,0.f};
    f32x4 acc10 = {0.f,0.f,0.f,0.f}, acc11 = {0.f,0.f,0.f,0.f};

    // B: p = p0 + w*16 + ks*4 + kq, j = j0 + m (+16 for j-chain 1)
    const float* wbase = W + (size_t)(p0 + w * 16 + kq) * 1280 + (size_t)(j0 + m) * 8;

    #pragma unroll
    for (int ks = 0; ks < 4; ++ks) {
        const short8 af0 =
            *reinterpret_cast<const short8*>(&As[m][w * 128 + ks * 32 + kq * 8]);
        const short8 af1 =
            *reinterpret_cast<const short8*>(&As[m + 16][w * 128 + ks * 32 + kq * 8]);
        const float* wp = wbase + (size_t)ks * 4 * 1280;
        const f32x4 a0 = *reinterpret_cast<const f32x4*>(wp);
        const f32x4 a1 = *reinterpret_cast<const f32x4*>(wp + 4);
        const f32x4 c0 = *reinterpret_cast<const f32x4*>(wp + 128);
        const f32x4 c1 = *reinterpret_cast<const f32x4*>(wp + 132);
        short8 bf0, bf1;
        #pragma unroll
        for (int e = 0; e < 4; ++e) {
            bf0[e]     = f2bf(a0[e]);
            bf0[e + 4] = f2bf(a1[e]);
            bf1[e]     = f2bf(c0[e]);
            bf1[e + 4] = f2bf(c1[e]);
        }
        acc00 = __builtin_amdgcn_mfma_f32_16x16x32_bf16(af0, bf0, acc00, 0, 0, 0);
        acc01 = __builtin_amdgcn_mfma_f32_16x16x32_bf16(af0, bf1, acc01, 0, 0, 0);
        acc10 = __builtin_amdgcn_mfma_f32_16x16x32_bf16(af1, bf0, acc10, 0, 0, 0);
        acc11 = __builtin_amdgcn_mfma_f32_16x16x32_bf16(af1, bf1, acc11, 0, 0, 0);
    }

    __syncthreads();   // all As reads done -> safe to reuse LDS as redux

    // ---- cross-wave split-K reduce (deterministic order w = 0..3) ----
    // redux[w][lane][c]: lane = kq*16 + m (kq = D-row quarter, m = j col),
    // c = bi*8 + ji*4 + r  (bi = b half, ji = j half, r = D reg)
    #pragma unroll
    for (int r = 0; r < 4; ++r) {
        redux[w][lane][r]      = acc00[r];
        redux[w][lane][r + 4]  = acc01[r];
        redux[w][lane][r + 8]  = acc10[r];
        redux[w][lane][r + 12] = acc11[r];
    }
    __syncthreads();

    // ---- coalesced float4 partial stores: 256 thr x 4 floats = 1024 ----
    {
        const int bl = tid >> 3;        // local b 0..31
        const int q  = tid & 7;         // j-quad 0..7
        const int ji = q >> 2;          // j half
        const int mq = q & 3;           // m quad
        const int bi  = bl >> 4;        // b half
        const int kqd = (bl >> 2) & 3;  // D-row quarter
        const int r   = bl & 3;         // D reg
        const int c   = bi * 8 + ji * 4 + r;
        f32x4 v;
        #pragma unroll
        for (int u = 0; u < 4; ++u) {
            const int ln = kqd * 16 + mq * 4 + u;
            v[u] = redux[0][ln][c] + redux[1][ln][c]
                 + redux[2][ln][c] + redux[3][ln][c];
        }
        *reinterpret_cast<f32x4*>(
            &part[((size_t)(b0 + bl) * SG + sg) * J_J + j0 + q * 4]) = v;
    }
}

// ---------------------------------------------------------------------------
// Kernel 2: reduce partials over slices + squash -> out.
// grid 256 (one b each), 128 threads. float4 loads; 3 slice-thirds in
// parallel (threads 0..119), LDS fan-in, squash over the L axis.
// ---------------------------------------------------------------------------
__global__ __launch_bounds__(128) void reduce_squash(const float* __restrict__ part,
                                                     float* __restrict__ out) {
    const int b   = blockIdx.x;
    const int tid = threadIdx.x;
    __shared__ f32x4 psum[3][40];
    __shared__ float sld[J_J];
    __shared__ float scl[16];

    const f32x4* p4 = reinterpret_cast<const f32x4*>(part + (size_t)b * SG * J_J);
    const int jq  = tid % 40;
    const int sgt = tid / 40;       // 0..2 active (threads 120..127 idle)
    if (sgt < 3) {
        f32x4 s = {0.f, 0.f, 0.f, 0.f};
        #pragma unroll
        for (int si = 0; si < 6; ++si)
            s += p4[(sgt * 6 + si) * 40 + jq];
        psum[sgt][jq] = s;
    }
    __syncthreads();
    if (tid < 40) {
        const f32x4 t = psum[0][tid] + psum[1][tid] + psum[2][tid];
        *reinterpret_cast<f32x4*>(&sld[tid * 4]) = t;
    }
    __syncthreads();
    if (tid < 16) {
        float ms = 0.f;
        #pragma unroll
        for (int l = 0; l < L_L; ++l) {
            const float v = sld[l * 16 + tid];
            ms = fmaf(v, v, ms);
        }
        scl[tid] = sqrtf(ms) / (1.0f + ms);
    }
    __syncthreads();
    out[(size_t)b * J_J + tid] = sld[tid] * scl[tid & 15];
    if (tid < 32) {
        const int j = 128 + tid;
        out[(size_t)b * J_J + j] = sld[j] * scl[j & 15];
    }
}

// ---------------------------------------------------------------------------
extern "C" void kernel_launch(void* const* d_in, const int* in_sizes, int n_in,
                              void* d_out, int out_size, void* d_ws, size_t ws_size,
                              hipStream_t stream) {
    const float* x = (const float*)d_in[0];   // (256, 8, 1152)
    const float* W = (const float*)d_in[1];   // (1, 1152, 10, 16, 8)
    float* out = (float*)d_out;               // (256, 10, 16)

    float* part = (float*)d_ws;               // [256][18][160] fp32 = 2.95 MB

    dim3 gg(B_TOT / 32, SG, JG);
    gemm_direct<<<gg, 256, 0, stream>>>(x, W, part);

    reduce_squash<<<B_TOT, 128, 0, stream>>>(part, out);
}